// Round 19
// baseline (146.979 us; speedup 1.0000x reference)
//
#include <hip/hip_runtime.h>
#include <hip/hip_bf16.h>
#include <stdint.h>

#define DIM 1024
#define SEQ 2048
#define NB 4
#define HEADS 8
#define HD 128
#define ROWS (NB*SEQ)   // 8192

typedef __attribute__((ext_vector_type(8))) short bf16x8;
typedef __attribute__((ext_vector_type(4))) float f32x4;
typedef __attribute__((ext_vector_type(16))) float f32x16;

#define VMCNT(n) asm volatile("s_waitcnt vmcnt(" #n ")" ::: "memory")
#define SBAR()   __builtin_amdgcn_s_barrier()
#define SCHED0() __builtin_amdgcn_sched_barrier(0)

static __device__ __forceinline__ unsigned short f2bf(float f){
  union { float f; unsigned int u; } x; x.f = f;
  unsigned int r = x.u + 0x7fffu + ((x.u >> 16) & 1u);
  return (unsigned short)(r >> 16);
}

static __device__ __forceinline__ void gld_lds16(const void* g, void* l){
  __builtin_amdgcn_global_load_lds(
      (const __attribute__((address_space(1))) void*)g,
      (__attribute__((address_space(3))) void*)l,
      16, 0, 0);
}

// ---------------- merged prep: cast x | transpose 3 weights | exp(w_aft) per-wave ----------
__global__ void k_prep(const float* __restrict__ x,
                       const float* __restrict__ Wk, const float* __restrict__ Wv,
                       const float* __restrict__ Wo, const float* __restrict__ waft,
                       unsigned short* __restrict__ xb,
                       unsigned short* __restrict__ Tk, unsigned short* __restrict__ Tv,
                       unsigned short* __restrict__ To, unsigned short* __restrict__ ewb){
  __shared__ float tile[64][65];
  const int B = blockIdx.x;
  const int tid = threadIdx.x;
  if (B < 2048){
    for (int i = B*256 + tid; i < ROWS*DIM/4; i += 2048*256){
      const float4 v = reinterpret_cast<const float4*>(x)[i];
      ushort4 o;
      o.x = f2bf(v.x); o.y = f2bf(v.y); o.z = f2bf(v.z); o.w = f2bf(v.w);
      reinterpret_cast<ushort4*>(xb)[i] = o;
    }
  } else if (B < 2816){
    const int D = B - 2048;
    const int z = D >> 8;
    const int rem = D & 255;
    const int bo = (rem & 15) * 64;
    const int bi = (rem >> 4) * 64;
    const float* W = (z == 0) ? Wk : (z == 1) ? Wv : Wo;
    unsigned short* WT = (z == 0) ? Tk : (z == 1) ? Tv : To;
    #pragma unroll
    for (int it = 0; it < 16; ++it){
      int f = it*256 + tid;
      int r = f >> 6, c = f & 63;
      tile[r][c] = W[(size_t)(bi + r) * DIM + bo + c];
    }
    __syncthreads();
    #pragma unroll
    for (int it = 0; it < 16; ++it){
      int f = it*256 + tid;
      int r = f >> 6, c = f & 63;
      WT[(size_t)(bo + r) * DIM + bi + c] = f2bf(tile[c][r]);
    }
  } else {
    const int row = (B - 2816) * 4 + (tid >> 6);
    const int lane = tid & 63;
    const int t = row & 2047;
    const int h = row >> 11;
    const float* src = waft + ((size_t)h*SEQ + t) * SEQ;
    unsigned short* dst = ewb + ((size_t)h*SEQ + t) * SEQ;
    const int smax4 = ((t & ~127) + 128) >> 2;
    for (int i = lane; i < smax4; i += 64){
      const float4 w4 = reinterpret_cast<const float4*>(src)[i];
      const int s = i * 4;
      ushort4 o;
      o.x = (s+0 <= t) ? f2bf(__expf(w4.x)) : (unsigned short)0;
      o.y = (s+1 <= t) ? f2bf(__expf(w4.y)) : (unsigned short)0;
      o.z = (s+2 <= t) ? f2bf(__expf(w4.z)) : (unsigned short)0;
      o.w = (s+3 <= t) ? f2bf(__expf(w4.w)) : (unsigned short)0;
      reinterpret_cast<ushort4*>(dst)[i] = o;
    }
  }
}

// ---------------- fused K/V projection: 1-barrier-pair K-step, B-frags hoisted (R17) --------
__global__ __launch_bounds__(512) void k_proj(
    const unsigned short* __restrict__ xb,
    const unsigned short* __restrict__ wkt,
    const unsigned short* __restrict__ wvt,
    const float* __restrict__ bk,
    const float* __restrict__ bv,
    unsigned short* __restrict__ ekb)
{
  __shared__ __align__(16) char smem[131072];
  unsigned short* Asl = (unsigned short*)smem;            // [2][256*64]
  unsigned short* Bsl = (unsigned short*)(smem + 65536);  // [2][256*64]
  float* xch = (float*)smem;                              // epilogue scratch [256][128]

  const int tid  = threadIdx.x;
  const int lane = tid & 63;
  const int lo   = lane & 15;
  const int hi   = lane >> 4;
  const int wid  = tid >> 6;
  const int wm   = wid >> 2;
  const int wn   = wid & 3;
  const int D    = blockIdx.x;
  const int mb   = D >> 3;
  const int cb   = D & 7;
  const int row0 = mb * 256;
  const int col0k = cb * 128;

  f32x4 acc[8][4] = {};

  auto stage_unit = [&](int kt, int slot, int u){
    const int half = u & 1;
    const bool isB = (u >> 1) != 0;
    unsigned short* lb = (isB ? Bsl : Asl) + slot*(256*64) + half*(128*64);
    const unsigned short* gb;
    if (!isB)           gb = xb  + (size_t)(row0 + half*128)*DIM + kt*64;
    else if (half == 0) gb = wkt + (size_t)col0k*DIM + kt*64;
    else                gb = wvt + (size_t)col0k*DIM + kt*64;
    #pragma unroll
    for (int it = 0; it < 2; ++it){
      const int po = (it*512 + tid)*16;
      const int r  = po >> 7;
      const int k2 = (po & 127) ^ ((r & 7) << 4);
      gld_lds16(gb + (size_t)r*DIM + (k2 >> 1), (char*)lb + po);
    }
  };

  #pragma unroll
  for (int u = 0; u < 4; ++u) stage_unit(0, 0, u);

  for (int t = 0; t < 16; ++t){
    const int s = t & 1;
    const bool nxt = (t + 1 < 16);
    const char* Ab = (const char*)(Asl + s*(256*64));
    const char* Bb = (const char*)(Bsl + s*(256*64));
    if (nxt){
      stage_unit(t + 1, s ^ 1, 0);
      stage_unit(t + 1, s ^ 1, 1);
      VMCNT(4);
    } else {
      VMCNT(0);
    }
    SCHED0();
    SBAR();
    SCHED0();
    bf16x8 b[4][2];
    #pragma unroll
    for (int nf = 0; nf < 4; ++nf){
      const int R = wn*64 + nf*16 + lo;
      #pragma unroll
      for (int ks = 0; ks < 2; ++ks){
        const int K2 = (ks*64 + hi*16) ^ ((R & 7) << 4);
        b[nf][ks] = *reinterpret_cast<const bf16x8*>(Bb + R*128 + K2);
      }
    }
    bf16x8 a0[4][2];
    #pragma unroll
    for (int mf = 0; mf < 4; ++mf){
      const int R = wm*128 + mf*16 + lo;
      #pragma unroll
      for (int ks = 0; ks < 2; ++ks){
        const int K2 = (ks*64 + hi*16) ^ ((R & 7) << 4);
        a0[mf][ks] = *reinterpret_cast<const bf16x8*>(Ab + R*128 + K2);
      }
    }
    if (nxt){
      stage_unit(t + 1, s ^ 1, 2);
      stage_unit(t + 1, s ^ 1, 3);
    }
    __builtin_amdgcn_s_setprio(1);
    #pragma unroll
    for (int ks = 0; ks < 2; ++ks)
      #pragma unroll
      for (int mf = 0; mf < 4; ++mf)
        #pragma unroll
        for (int nf = 0; nf < 4; ++nf)
          acc[mf][nf] = __builtin_amdgcn_mfma_f32_16x16x32_bf16(
              a0[mf][ks], b[nf][ks], acc[mf][nf], 0, 0, 0);
    __builtin_amdgcn_s_setprio(0);
    bf16x8 a1[4][2];
    #pragma unroll
    for (int mf = 0; mf < 4; ++mf){
      const int R = wm*128 + (4 + mf)*16 + lo;
      #pragma unroll
      for (int ks = 0; ks < 2; ++ks){
        const int K2 = (ks*64 + hi*16) ^ ((R & 7) << 4);
        a1[mf][ks] = *reinterpret_cast<const bf16x8*>(Ab + R*128 + K2);
      }
    }
    __builtin_amdgcn_s_setprio(1);
    #pragma unroll
    for (int ks = 0; ks < 2; ++ks)
      #pragma unroll
      for (int mf = 0; mf < 4; ++mf)
        #pragma unroll
        for (int nf = 0; nf < 4; ++nf)
          acc[4+mf][nf] = __builtin_amdgcn_mfma_f32_16x16x32_bf16(
              a1[mf][ks], b[nf][ks], acc[4+mf][nf], 0, 0, 0);
    __builtin_amdgcn_s_setprio(0);
    SCHED0();
    SBAR();
  }

  __syncthreads();
  if (wn >= 2){
    #pragma unroll
    for (int mf = 0; mf < 8; ++mf){
      const int rloc = wm*128 + mf*16 + hi*4;
      #pragma unroll
      for (int nf = 0; nf < 4; ++nf){
        const int cv = (wn - 2)*64 + nf*16 + lo;
        #pragma unroll
        for (int jj = 0; jj < 4; ++jj)
          xch[(size_t)(rloc + jj)*128 + cv] = acc[mf][nf][jj];
      }
    }
  }
  __syncthreads();
  if (wn < 2){
    #pragma unroll
    for (int nf = 0; nf < 4; ++nf){
      const int ck = wn*64 + nf*16 + lo;
      const int c  = col0k + ck;
      const int h  = c >> 7;
      const int d  = c & 127;
      const float bkc = bk[c];
      const float bvc = bv[c];
      #pragma unroll
      for (int mf = 0; mf < 8; ++mf){
        const int rloc = wm*128 + mf*16 + hi*4;
        const int r = row0 + rloc;
        const int n = r >> 11;
        const int sidx = r & 2047;
        ushort4 pk, pv;
        #pragma unroll
        for (int jj = 0; jj < 4; ++jj){
          const float kval = acc[mf][nf][jj] + bkc;
          const float vval = xch[(size_t)(rloc + jj)*128 + ck] + bvc;
          const float ek = __expf(kval);
          ((unsigned short*)&pk)[jj] = f2bf(ek);
          ((unsigned short*)&pv)[jj] = f2bf(ek * vval);
        }
        const size_t idx = ((size_t)h*1024 + n*256 + d) * SEQ + sidx;
        *reinterpret_cast<ushort4*>(&ekb[idx]) = pk;
        *reinterpret_cast<ushort4*>(&ekb[idx + (size_t)128*SEQ]) = pv;
      }
    }
  }
}

// ---------------- AFT causal core: 3-slot 1-barrier K-step, 32x32x16 MFMA, fused div -------
// A/B frag: lane l -> row/col = l&31, k = (l>>5)*8+j. C/D: col=lane&31,
// row = (reg&3)+8*(reg>>2)+4*(lane>>5) (m74/m101). Wave tile 64x64 = [2][2] frags.
__global__ __launch_bounds__(512) void k_core(
    const unsigned short* __restrict__ ewb,
    const unsigned short* __restrict__ ekb,
    unsigned short* __restrict__ aftb)
{
  __shared__ __align__(16) char smem[147456];             // A[3][128*64] + B[3][256*64]
  unsigned short* Asl = (unsigned short*)smem;            // 48 KB
  unsigned short* Bsl = (unsigned short*)(smem + 49152);  // 96 KB
  float* xch = (float*)smem;                              // epilogue [128][129] f32

  const int tid  = threadIdx.x;
  const int lane = tid & 63;
  const int l31  = lane & 31;
  const int l5   = lane >> 5;     // 0..1
  const int wid  = tid >> 6;
  const int wm   = wid >> 2;       // 0..1
  const int wn   = wid & 3;        // 0..3
  const int D  = blockIdx.x;
  const int h  = D & 7;
  const int r_ = D >> 3;
  const int p  = r_ >> 2;
  const int n  = r_ & 3;

  const unsigned short* slab = ekb + ((size_t)h*1024 + n*256) * SEQ;

  #pragma unroll
  for (int half = 0; half < 2; ++half){
    const int tt = half ? p : (15 - p);
    const int t0 = tt * 128;
    const int nst = 2*tt + 2;
    const unsigned short* abase = ewb + ((size_t)h*SEQ + t0) * SEQ;

    f32x16 acc[2][2] = {};

    auto stage_unit = [&](int st, int slot, int u){
      const int s0 = st * 64;
      const int po = tid * 16;
      const int r  = po >> 7;
      const int k2 = (po & 127) ^ ((r & 7) << 4);
      if (u < 2){
        unsigned short* lb = Asl + slot*(128*64) + u*(64*64);
        gld_lds16(abase + (size_t)(u*64 + r)*SEQ + s0 + (k2 >> 1), (char*)lb + po);
      } else {
        unsigned short* lb = Bsl + slot*(256*64) + (u-2)*(64*64);
        gld_lds16(slab + (size_t)((u-2)*64 + r)*SEQ + s0 + (k2 >> 1), (char*)lb + po);
      }
    };

    #pragma unroll
    for (int u = 0; u < 6; ++u) stage_unit(0, 0, u);

    int slot_cur = 0;
    for (int t = 0; t < nst; ++t){
      const bool nxt = (t + 1 < nst);
      const int slot_nxt = (slot_cur == 2) ? 0 : slot_cur + 1;
      const char* Ab = (const char*)(Asl + slot_cur*(128*64));
      const char* Bb = (const char*)(Bsl + slot_cur*(256*64));
      if (nxt){
        #pragma unroll
        for (int u = 0; u < 6; ++u) stage_unit(t + 1, slot_nxt, u);
        VMCNT(6);
      } else {
        VMCNT(0);
      }
      SCHED0();
      SBAR();
      SCHED0();
      // B frags: [nfr][kk] — col = wn*64 + nfr*32 + l31, k-slice kk of 4
      bf16x8 b[2][4];
      #pragma unroll
      for (int nfr = 0; nfr < 2; ++nfr){
        const int R = wn*64 + nfr*32 + l31;
        #pragma unroll
        for (int kk = 0; kk < 4; ++kk){
          const int K2 = (kk*32 + l5*16) ^ ((R & 7) << 4);
          b[nfr][kk] = *reinterpret_cast<const bf16x8*>(Bb + R*128 + K2);
        }
      }
      bf16x8 a0[4];
      {
        const int R = wm*64 + l31;          // mfr = 0
        #pragma unroll
        for (int kk = 0; kk < 4; ++kk){
          const int K2 = (kk*32 + l5*16) ^ ((R & 7) << 4);
          a0[kk] = *reinterpret_cast<const bf16x8*>(Ab + R*128 + K2);
        }
      }
      __builtin_amdgcn_s_setprio(1);
      #pragma unroll
      for (int kk = 0; kk < 4; ++kk)
        #pragma unroll
        for (int nfr = 0; nfr < 2; ++nfr)
          acc[0][nfr] = __builtin_amdgcn_mfma_f32_32x32x16_bf16(
              a0[kk], b[nfr][kk], acc[0][nfr], 0, 0, 0);
      __builtin_amdgcn_s_setprio(0);
      bf16x8 a1[4];
      {
        const int R = wm*64 + 32 + l31;     // mfr = 1
        #pragma unroll
        for (int kk = 0; kk < 4; ++kk){
          const int K2 = (kk*32 + l5*16) ^ ((R & 7) << 4);
          a1[kk] = *reinterpret_cast<const bf16x8*>(Ab + R*128 + K2);
        }
      }
      __builtin_amdgcn_s_setprio(1);
      #pragma unroll
      for (int kk = 0; kk < 4; ++kk)
        #pragma unroll
        for (int nfr = 0; nfr < 2; ++nfr)
          acc[1][nfr] = __builtin_amdgcn_mfma_f32_32x32x16_bf16(
              a1[kk], b[nfr][kk], acc[1][nfr], 0, 0, 0);
      __builtin_amdgcn_s_setprio(0);
      slot_cur = slot_nxt;
    }

    // ---- fused division epilogue (32x32 C layout) ----
    __syncthreads();
    if (wn >= 2){
      #pragma unroll
      for (int mfr = 0; mfr < 2; ++mfr){
        #pragma unroll
        for (int nfr = 0; nfr < 2; ++nfr){
          const int dv = (wn - 2)*64 + nfr*32 + l31;   // num col 0..127
          #pragma unroll
          for (int reg = 0; reg < 16; ++reg){
            const int rloc = wm*64 + mfr*32 + (reg & 3) + 8*(reg >> 2) + 4*l5;
            xch[(size_t)rloc*129 + dv] = acc[mfr][nfr][reg];
          }
        }
      }
    }
    __syncthreads();
    if (wn < 2){
      #pragma unroll
      for (int mfr = 0; mfr < 2; ++mfr){
        #pragma unroll
        for (int nfr = 0; nfr < 2; ++nfr){
          const int d = wn*64 + nfr*32 + l31;          // den col 0..127
          #pragma unroll
          for (int reg = 0; reg < 16; ++reg){
            const int rloc = wm*64 + mfr*32 + (reg & 3) + 8*(reg >> 2) + 4*l5;
            const int t = t0 + rloc;
            const float num = xch[(size_t)rloc*129 + d];
            aftb[((size_t)n*SEQ + t)*DIM + h*HD + d] = f2bf(num / acc[mfr][nfr][reg]);
          }
        }
      }
    }
    __syncthreads();   // xch reads done before next half's staging reuses smem
  }
}

// ---------------- output projection: 3-slot, ONE barrier per K-step (R18) ----------------
__global__ __launch_bounds__(512) void k_out(
    const unsigned short* __restrict__ aftb,
    const unsigned short* __restrict__ wot,
    const float* __restrict__ bo,
    float* __restrict__ out)
{
  __shared__ __align__(16) char smem[147456];
  unsigned short* Asl = (unsigned short*)smem;            // [3][128*64]
  unsigned short* Bsl = (unsigned short*)(smem + 49152);  // [3][256*64]

  const int tid  = threadIdx.x;
  const int lane = tid & 63;
  const int lo   = lane & 15;
  const int hi   = lane >> 4;
  const int wid  = tid >> 6;
  const int wm   = wid >> 2;
  const int wn   = wid & 3;
  const int D    = blockIdx.x;
  const int row0 = (D >> 2) * 128;
  const int col0 = (D & 3) * 256;

  f32x4 acc[4][4] = {};

  auto stage_unit = [&](int kt, int slot, int u){
    const int po = tid * 16;
    const int r  = po >> 7;
    const int k2 = (po & 127) ^ ((r & 7) << 4);
    if (u < 2){
      unsigned short* lb = Asl + slot*(128*64) + u*(64*64);
      gld_lds16(aftb + (size_t)(row0 + u*64 + r)*DIM + kt*64 + (k2 >> 1), (char*)lb + po);
    } else {
      unsigned short* lb = Bsl + slot*(256*64) + (u-2)*(64*64);
      gld_lds16(wot + (size_t)(col0 + (u-2)*64 + r)*DIM + kt*64 + (k2 >> 1), (char*)lb + po);
    }
  };

  #pragma unroll
  for (int u = 0; u < 6; ++u) stage_unit(0, 0, u);

  int slot_cur = 0;
  for (int t = 0; t < 16; ++t){
    const bool nxt = (t + 1 < 16);
    const int slot_nxt = (slot_cur == 2) ? 0 : slot_cur + 1;
    const char* Ab = (const char*)(Asl + slot_cur*(128*64));
    const char* Bb = (const char*)(Bsl + slot_cur*(256*64));
    if (nxt){
      #pragma unroll
      for (int u = 0; u < 6; ++u) stage_unit(t + 1, slot_nxt, u);
      VMCNT(6);
    } else {
      VMCNT(0);
    }
    SCHED0();
    SBAR();
    SCHED0();
    bf16x8 b[4][2];
    #pragma unroll
    for (int nf = 0; nf < 4; ++nf){
      const int R = wn*64 + nf*16 + lo;
      #pragma unroll
      for (int ks = 0; ks < 2; ++ks){
        const int K2 = (ks*64 + hi*16) ^ ((R & 7) << 4);
        b[nf][ks] = *reinterpret_cast<const bf16x8*>(Bb + R*128 + K2);
      }
    }
    bf16x8 a0[2][2];
    #pragma unroll
    for (int mf = 0; mf < 2; ++mf){
      const int R = wm*64 + mf*16 + lo;
      #pragma unroll
      for (int ks = 0; ks < 2; ++ks){
        const int K2 = (ks*64 + hi*16) ^ ((R & 7) << 4);
        a0[mf][ks] = *reinterpret_cast<const bf16x8*>(Ab + R*128 + K2);
      }
    }
    __builtin_amdgcn_s_setprio(1);
    #pragma unroll
    for (int ks = 0; ks < 2; ++ks)
      #pragma unroll
      for (int mf = 0; mf < 2; ++mf)
        #pragma unroll
        for (int nf = 0; nf < 4; ++nf)
          acc[mf][nf] = __builtin_amdgcn_mfma_f32_16x16x32_bf16(
              a0[mf][ks], b[nf][ks], acc[mf][nf], 0, 0, 0);
    __builtin_amdgcn_s_setprio(0);
    bf16x8 a1[2][2];
    #pragma unroll
    for (int mf = 0; mf < 2; ++mf){
      const int R = wm*64 + (2 + mf)*16 + lo;
      #pragma unroll
      for (int ks = 0; ks < 2; ++ks){
        const int K2 = (ks*64 + hi*16) ^ ((R & 7) << 4);
        a1[mf][ks] = *reinterpret_cast<const bf16x8*>(Ab + R*128 + K2);
      }
    }
    __builtin_amdgcn_s_setprio(1);
    #pragma unroll
    for (int ks = 0; ks < 2; ++ks)
      #pragma unroll
      for (int mf = 0; mf < 2; ++mf)
        #pragma unroll
        for (int nf = 0; nf < 4; ++nf)
          acc[2+mf][nf] = __builtin_amdgcn_mfma_f32_16x16x32_bf16(
              a1[mf][ks], b[nf][ks], acc[2+mf][nf], 0, 0, 0);
    __builtin_amdgcn_s_setprio(0);
    slot_cur = slot_nxt;
  }

  #pragma unroll
  for (int nf = 0; nf < 4; ++nf){
    const int c = col0 + wn*64 + nf*16 + lo;
    const float boc = bo[c];
    #pragma unroll
    for (int mf = 0; mf < 4; ++mf){
      #pragma unroll
      for (int jj = 0; jj < 4; ++jj){
        const int r = row0 + wm*64 + mf*16 + hi*4 + jj;
        out[(size_t)r*DIM + c] = acc[mf][nf][jj] + boc;
      }
    }
  }
}

extern "C" void kernel_launch(void* const* d_in, const int* in_sizes, int n_in,
                              void* d_out, int out_size, void* d_ws, size_t ws_size,
                              hipStream_t stream){
  const float* x    = (const float*)d_in[0];
  const float* Wk   = (const float*)d_in[1];
  const float* bk   = (const float*)d_in[2];
  const float* Wv   = (const float*)d_in[3];
  const float* bv   = (const float*)d_in[4];
  const float* waft = (const float*)d_in[5];
  const float* Wo   = (const float*)d_in[6];
  const float* bo   = (const float*)d_in[7];
  float* out = (float*)d_out;

  char* w = (char*)d_ws;
  unsigned short* xb   = (unsigned short*)w; w += (size_t)ROWS*DIM*2;       // 16 MB
  unsigned short* wkt  = (unsigned short*)w; w += (size_t)DIM*DIM*2;        // 2 MB
  unsigned short* wvt  = (unsigned short*)w; w += (size_t)DIM*DIM*2;        // 2 MB
  unsigned short* wot  = (unsigned short*)w; w += (size_t)DIM*DIM*2;        // 2 MB
  unsigned short* ekb  = (unsigned short*)w; w += (size_t)HEADS*1024*SEQ*2; // 32 MB
  unsigned short* aftb = (unsigned short*)w; w += (size_t)ROWS*DIM*2;       // 16 MB
  unsigned short* ewb  = (unsigned short*)w; w += (size_t)HEADS*SEQ*SEQ*2;  // 64 MB

  k_prep<<<6912, 256, 0, stream>>>(x, Wk, Wv, Wo, waft, xb, wkt, wvt, wot, ewb);
  k_proj<<<256, 512, 0, stream>>>(xb, wkt, wvt, bk, bv, ekb);
  k_core<<<256, 512, 0, stream>>>(ewb, ekb, aftb);
  k_out<<<256, 512, 0, stream>>>(aftb, wot, bo, out);
}

// Round 20
// 140.775 us; speedup vs baseline: 1.0441x; 1.0441x over previous
//
#include <hip/hip_runtime.h>
#include <hip/hip_bf16.h>
#include <stdint.h>

#define DIM 1024
#define SEQ 2048
#define NB 4
#define HEADS 8
#define HD 128
#define ROWS (NB*SEQ)   // 8192

typedef __attribute__((ext_vector_type(8))) short bf16x8;
typedef __attribute__((ext_vector_type(4))) float f32x4;

#define VMCNT(n) asm volatile("s_waitcnt vmcnt(" #n ")" ::: "memory")
#define SBAR()   __builtin_amdgcn_s_barrier()
#define SCHED0() __builtin_amdgcn_sched_barrier(0)

static __device__ __forceinline__ unsigned short f2bf(float f){
  union { float f; unsigned int u; } x; x.f = f;
  unsigned int r = x.u + 0x7fffu + ((x.u >> 16) & 1u);
  return (unsigned short)(r >> 16);
}

static __device__ __forceinline__ void gld_lds16(const void* g, void* l){
  __builtin_amdgcn_global_load_lds(
      (const __attribute__((address_space(1))) void*)g,
      (__attribute__((address_space(3))) void*)l,
      16, 0, 0);
}

// ---------------- merged prep: cast x | transpose 3 weights | exp(w_aft) per-wave ----------
__global__ void k_prep(const float* __restrict__ x,
                       const float* __restrict__ Wk, const float* __restrict__ Wv,
                       const float* __restrict__ Wo, const float* __restrict__ waft,
                       unsigned short* __restrict__ xb,
                       unsigned short* __restrict__ Tk, unsigned short* __restrict__ Tv,
                       unsigned short* __restrict__ To, unsigned short* __restrict__ ewb){
  __shared__ float tile[64][65];
  const int B = blockIdx.x;
  const int tid = threadIdx.x;
  if (B < 2048){
    for (int i = B*256 + tid; i < ROWS*DIM/4; i += 2048*256){
      const float4 v = reinterpret_cast<const float4*>(x)[i];
      ushort4 o;
      o.x = f2bf(v.x); o.y = f2bf(v.y); o.z = f2bf(v.z); o.w = f2bf(v.w);
      reinterpret_cast<ushort4*>(xb)[i] = o;
    }
  } else if (B < 2816){
    const int D = B - 2048;
    const int z = D >> 8;
    const int rem = D & 255;
    const int bo = (rem & 15) * 64;
    const int bi = (rem >> 4) * 64;
    const float* W = (z == 0) ? Wk : (z == 1) ? Wv : Wo;
    unsigned short* WT = (z == 0) ? Tk : (z == 1) ? Tv : To;
    #pragma unroll
    for (int it = 0; it < 16; ++it){
      int f = it*256 + tid;
      int r = f >> 6, c = f & 63;
      tile[r][c] = W[(size_t)(bi + r) * DIM + bo + c];
    }
    __syncthreads();
    #pragma unroll
    for (int it = 0; it < 16; ++it){
      int f = it*256 + tid;
      int r = f >> 6, c = f & 63;
      WT[(size_t)(bo + r) * DIM + bi + c] = f2bf(tile[c][r]);
    }
  } else {
    const int row = (B - 2816) * 4 + (tid >> 6);
    const int lane = tid & 63;
    const int t = row & 2047;
    const int h = row >> 11;
    const float* src = waft + ((size_t)h*SEQ + t) * SEQ;
    unsigned short* dst = ewb + ((size_t)h*SEQ + t) * SEQ;
    const int smax4 = ((t & ~127) + 128) >> 2;
    for (int i = lane; i < smax4; i += 64){
      const float4 w4 = reinterpret_cast<const float4*>(src)[i];
      const int s = i * 4;
      ushort4 o;
      o.x = (s+0 <= t) ? f2bf(__expf(w4.x)) : (unsigned short)0;
      o.y = (s+1 <= t) ? f2bf(__expf(w4.y)) : (unsigned short)0;
      o.z = (s+2 <= t) ? f2bf(__expf(w4.z)) : (unsigned short)0;
      o.w = (s+3 <= t) ? f2bf(__expf(w4.w)) : (unsigned short)0;
      reinterpret_cast<ushort4*>(dst)[i] = o;
    }
  }
}

// ---------------- fused K/V projection: 1-barrier-pair K-step, B-frags hoisted (R17) --------
__global__ __launch_bounds__(512) void k_proj(
    const unsigned short* __restrict__ xb,
    const unsigned short* __restrict__ wkt,
    const unsigned short* __restrict__ wvt,
    const float* __restrict__ bk,
    const float* __restrict__ bv,
    unsigned short* __restrict__ ekb)
{
  __shared__ __align__(16) char smem[131072];
  unsigned short* Asl = (unsigned short*)smem;            // [2][256*64]
  unsigned short* Bsl = (unsigned short*)(smem + 65536);  // [2][256*64]
  float* xch = (float*)smem;                              // epilogue scratch [256][128]

  const int tid  = threadIdx.x;
  const int lane = tid & 63;
  const int lo   = lane & 15;
  const int hi   = lane >> 4;
  const int wid  = tid >> 6;
  const int wm   = wid >> 2;
  const int wn   = wid & 3;
  const int D    = blockIdx.x;
  const int mb   = D >> 3;
  const int cb   = D & 7;
  const int row0 = mb * 256;
  const int col0k = cb * 128;

  f32x4 acc[8][4] = {};

  auto stage_unit = [&](int kt, int slot, int u){
    const int half = u & 1;
    const bool isB = (u >> 1) != 0;
    unsigned short* lb = (isB ? Bsl : Asl) + slot*(256*64) + half*(128*64);
    const unsigned short* gb;
    if (!isB)           gb = xb  + (size_t)(row0 + half*128)*DIM + kt*64;
    else if (half == 0) gb = wkt + (size_t)col0k*DIM + kt*64;
    else                gb = wvt + (size_t)col0k*DIM + kt*64;
    #pragma unroll
    for (int it = 0; it < 2; ++it){
      const int po = (it*512 + tid)*16;
      const int r  = po >> 7;
      const int k2 = (po & 127) ^ ((r & 7) << 4);
      gld_lds16(gb + (size_t)r*DIM + (k2 >> 1), (char*)lb + po);
    }
  };

  #pragma unroll
  for (int u = 0; u < 4; ++u) stage_unit(0, 0, u);

  for (int t = 0; t < 16; ++t){
    const int s = t & 1;
    const bool nxt = (t + 1 < 16);
    const char* Ab = (const char*)(Asl + s*(256*64));
    const char* Bb = (const char*)(Bsl + s*(256*64));
    if (nxt){
      stage_unit(t + 1, s ^ 1, 0);
      stage_unit(t + 1, s ^ 1, 1);
      VMCNT(4);
    } else {
      VMCNT(0);
    }
    SCHED0();
    SBAR();
    SCHED0();
    bf16x8 b[4][2];
    #pragma unroll
    for (int nf = 0; nf < 4; ++nf){
      const int R = wn*64 + nf*16 + lo;
      #pragma unroll
      for (int ks = 0; ks < 2; ++ks){
        const int K2 = (ks*64 + hi*16) ^ ((R & 7) << 4);
        b[nf][ks] = *reinterpret_cast<const bf16x8*>(Bb + R*128 + K2);
      }
    }
    bf16x8 a0[4][2];
    #pragma unroll
    for (int mf = 0; mf < 4; ++mf){
      const int R = wm*128 + mf*16 + lo;
      #pragma unroll
      for (int ks = 0; ks < 2; ++ks){
        const int K2 = (ks*64 + hi*16) ^ ((R & 7) << 4);
        a0[mf][ks] = *reinterpret_cast<const bf16x8*>(Ab + R*128 + K2);
      }
    }
    if (nxt){
      stage_unit(t + 1, s ^ 1, 2);
      stage_unit(t + 1, s ^ 1, 3);
    }
    __builtin_amdgcn_s_setprio(1);
    #pragma unroll
    for (int ks = 0; ks < 2; ++ks)
      #pragma unroll
      for (int mf = 0; mf < 4; ++mf)
        #pragma unroll
        for (int nf = 0; nf < 4; ++nf)
          acc[mf][nf] = __builtin_amdgcn_mfma_f32_16x16x32_bf16(
              a0[mf][ks], b[nf][ks], acc[mf][nf], 0, 0, 0);
    __builtin_amdgcn_s_setprio(0);
    bf16x8 a1[4][2];
    #pragma unroll
    for (int mf = 0; mf < 4; ++mf){
      const int R = wm*128 + (4 + mf)*16 + lo;
      #pragma unroll
      for (int ks = 0; ks < 2; ++ks){
        const int K2 = (ks*64 + hi*16) ^ ((R & 7) << 4);
        a1[mf][ks] = *reinterpret_cast<const bf16x8*>(Ab + R*128 + K2);
      }
    }
    __builtin_amdgcn_s_setprio(1);
    #pragma unroll
    for (int ks = 0; ks < 2; ++ks)
      #pragma unroll
      for (int mf = 0; mf < 4; ++mf)
        #pragma unroll
        for (int nf = 0; nf < 4; ++nf)
          acc[4+mf][nf] = __builtin_amdgcn_mfma_f32_16x16x32_bf16(
              a1[mf][ks], b[nf][ks], acc[4+mf][nf], 0, 0, 0);
    __builtin_amdgcn_s_setprio(0);
    SCHED0();
    SBAR();
  }

  __syncthreads();
  if (wn >= 2){
    #pragma unroll
    for (int mf = 0; mf < 8; ++mf){
      const int rloc = wm*128 + mf*16 + hi*4;
      #pragma unroll
      for (int nf = 0; nf < 4; ++nf){
        const int cv = (wn - 2)*64 + nf*16 + lo;
        #pragma unroll
        for (int jj = 0; jj < 4; ++jj)
          xch[(size_t)(rloc + jj)*128 + cv] = acc[mf][nf][jj];
      }
    }
  }
  __syncthreads();
  if (wn < 2){
    #pragma unroll
    for (int nf = 0; nf < 4; ++nf){
      const int ck = wn*64 + nf*16 + lo;
      const int c  = col0k + ck;
      const int h  = c >> 7;
      const int d  = c & 127;
      const float bkc = bk[c];
      const float bvc = bv[c];
      #pragma unroll
      for (int mf = 0; mf < 8; ++mf){
        const int rloc = wm*128 + mf*16 + hi*4;
        const int r = row0 + rloc;
        const int n = r >> 11;
        const int sidx = r & 2047;
        ushort4 pk, pv;
        #pragma unroll
        for (int jj = 0; jj < 4; ++jj){
          const float kval = acc[mf][nf][jj] + bkc;
          const float vval = xch[(size_t)(rloc + jj)*128 + ck] + bvc;
          const float ek = __expf(kval);
          ((unsigned short*)&pk)[jj] = f2bf(ek);
          ((unsigned short*)&pv)[jj] = f2bf(ek * vval);
        }
        const size_t idx = ((size_t)h*1024 + n*256 + d) * SEQ + sidx;
        *reinterpret_cast<ushort4*>(&ekb[idx]) = pk;
        *reinterpret_cast<ushort4*>(&ekb[idx + (size_t)128*SEQ]) = pv;
      }
    }
  }
}

// ---------------- AFT causal core: 3-slot, ONE barrier per K-step, fused division ----------
__global__ __launch_bounds__(512) void k_core(
    const unsigned short* __restrict__ ewb,
    const unsigned short* __restrict__ ekb,
    unsigned short* __restrict__ aftb)
{
  __shared__ __align__(16) char smem[147456];             // A[3][128*64] + B[3][256*64]
  unsigned short* Asl = (unsigned short*)smem;            // 48 KB
  unsigned short* Bsl = (unsigned short*)(smem + 49152);  // 96 KB
  float* xch = (float*)smem;                              // epilogue [128][129] f32

  const int tid  = threadIdx.x;
  const int lane = tid & 63;
  const int lo   = lane & 15;
  const int hi   = lane >> 4;
  const int wid  = tid >> 6;
  const int wm   = wid >> 2;       // 0..1
  const int wn   = wid & 3;        // 0..3
  const int D  = blockIdx.x;
  const int h  = D & 7;
  const int r_ = D >> 3;
  const int p  = r_ >> 2;
  const int n  = r_ & 3;

  const unsigned short* slab = ekb + ((size_t)h*1024 + n*256) * SEQ;

  #pragma unroll
  for (int half = 0; half < 2; ++half){
    const int tt = half ? p : (15 - p);
    const int t0 = tt * 128;
    const int nst = 2*tt + 2;
    const unsigned short* abase = ewb + ((size_t)h*SEQ + t0) * SEQ;

    f32x4 acc[4][4] = {};

    auto stage_unit = [&](int st, int slot, int u){
      const int s0 = st * 64;
      const int po = tid * 16;
      const int r  = po >> 7;
      const int k2 = (po & 127) ^ ((r & 7) << 4);
      if (u < 2){
        unsigned short* lb = Asl + slot*(128*64) + u*(64*64);
        gld_lds16(abase + (size_t)(u*64 + r)*SEQ + s0 + (k2 >> 1), (char*)lb + po);
      } else {
        unsigned short* lb = Bsl + slot*(256*64) + (u-2)*(64*64);
        gld_lds16(slab + (size_t)((u-2)*64 + r)*SEQ + s0 + (k2 >> 1), (char*)lb + po);
      }
    };

    #pragma unroll
    for (int u = 0; u < 6; ++u) stage_unit(0, 0, u);

    int slot_cur = 0;
    for (int t = 0; t < nst; ++t){
      const bool nxt = (t + 1 < nst);
      const int slot_nxt = (slot_cur == 2) ? 0 : slot_cur + 1;
      const char* Ab = (const char*)(Asl + slot_cur*(128*64));
      const char* Bb = (const char*)(Bsl + slot_cur*(256*64));
      if (nxt){
        #pragma unroll
        for (int u = 0; u < 6; ++u) stage_unit(t + 1, slot_nxt, u);
        VMCNT(6);
      } else {
        VMCNT(0);
      }
      SCHED0();
      SBAR();
      SCHED0();
      bf16x8 b[4][2];
      #pragma unroll
      for (int nf = 0; nf < 4; ++nf){
        const int R = wn*64 + nf*16 + lo;
        #pragma unroll
        for (int ks = 0; ks < 2; ++ks){
          const int K2 = (ks*64 + hi*16) ^ ((R & 7) << 4);
          b[nf][ks] = *reinterpret_cast<const bf16x8*>(Bb + R*128 + K2);
        }
      }
      bf16x8 a0[2][2];
      #pragma unroll
      for (int mf = 0; mf < 2; ++mf){
        const int R = wm*64 + mf*16 + lo;
        #pragma unroll
        for (int ks = 0; ks < 2; ++ks){
          const int K2 = (ks*64 + hi*16) ^ ((R & 7) << 4);
          a0[mf][ks] = *reinterpret_cast<const bf16x8*>(Ab + R*128 + K2);
        }
      }
      __builtin_amdgcn_s_setprio(1);
      #pragma unroll
      for (int ks = 0; ks < 2; ++ks)
        #pragma unroll
        for (int mf = 0; mf < 2; ++mf)
          #pragma unroll
          for (int nf = 0; nf < 4; ++nf)
            acc[mf][nf] = __builtin_amdgcn_mfma_f32_16x16x32_bf16(
                a0[mf][ks], b[nf][ks], acc[mf][nf], 0, 0, 0);
      __builtin_amdgcn_s_setprio(0);
      bf16x8 a1[2][2];
      #pragma unroll
      for (int mf = 0; mf < 2; ++mf){
        const int R = wm*64 + (2 + mf)*16 + lo;
        #pragma unroll
        for (int ks = 0; ks < 2; ++ks){
          const int K2 = (ks*64 + hi*16) ^ ((R & 7) << 4);
          a1[mf][ks] = *reinterpret_cast<const bf16x8*>(Ab + R*128 + K2);
        }
      }
      __builtin_amdgcn_s_setprio(1);
      #pragma unroll
      for (int ks = 0; ks < 2; ++ks)
        #pragma unroll
        for (int mf = 0; mf < 2; ++mf)
          #pragma unroll
          for (int nf = 0; nf < 4; ++nf)
            acc[2+mf][nf] = __builtin_amdgcn_mfma_f32_16x16x32_bf16(
                a1[mf][ks], b[nf][ks], acc[2+mf][nf], 0, 0, 0);
      __builtin_amdgcn_s_setprio(0);
      slot_cur = slot_nxt;
    }

    // ---- fused division epilogue ----
    __syncthreads();
    if (wn >= 2){
      #pragma unroll
      for (int mf = 0; mf < 4; ++mf){
        const int rloc = wm*64 + mf*16 + hi*4;
        #pragma unroll
        for (int nf = 0; nf < 4; ++nf){
          const int dv = (wn - 2)*64 + nf*16 + lo;     // num col 0..127
          #pragma unroll
          for (int jj = 0; jj < 4; ++jj)
            xch[(size_t)(rloc + jj)*129 + dv] = acc[mf][nf][jj];
        }
      }
    }
    __syncthreads();
    if (wn < 2){
      #pragma unroll
      for (int nf = 0; nf < 4; ++nf){
        const int d = wn*64 + nf*16 + lo;              // den col 0..127
        #pragma unroll
        for (int mf = 0; mf < 4; ++mf){
          const int rloc = wm*64 + mf*16 + hi*4;
          #pragma unroll
          for (int jj = 0; jj < 4; ++jj){
            const int t = t0 + rloc + jj;
            const float num = xch[(size_t)(rloc + jj)*129 + d];
            aftb[((size_t)n*SEQ + t)*DIM + h*HD + d] = f2bf(num / acc[mf][nf][jj]);
          }
        }
      }
    }
    __syncthreads();   // xch reads done before next half's staging reuses smem
  }
}

// ---------------- output projection: 3-slot, ONE barrier per K-step ----------------
__global__ __launch_bounds__(512) void k_out(
    const unsigned short* __restrict__ aftb,
    const unsigned short* __restrict__ wot,
    const float* __restrict__ bo,
    float* __restrict__ out)
{
  __shared__ __align__(16) char smem[147456];
  unsigned short* Asl = (unsigned short*)smem;            // [3][128*64]
  unsigned short* Bsl = (unsigned short*)(smem + 49152);  // [3][256*64]

  const int tid  = threadIdx.x;
  const int lane = tid & 63;
  const int lo   = lane & 15;
  const int hi   = lane >> 4;
  const int wid  = tid >> 6;
  const int wm   = wid >> 2;
  const int wn   = wid & 3;
  const int D    = blockIdx.x;
  const int row0 = (D >> 2) * 128;
  const int col0 = (D & 3) * 256;

  f32x4 acc[4][4] = {};

  auto stage_unit = [&](int kt, int slot, int u){
    const int po = tid * 16;
    const int r  = po >> 7;
    const int k2 = (po & 127) ^ ((r & 7) << 4);
    if (u < 2){
      unsigned short* lb = Asl + slot*(128*64) + u*(64*64);
      gld_lds16(aftb + (size_t)(row0 + u*64 + r)*DIM + kt*64 + (k2 >> 1), (char*)lb + po);
    } else {
      unsigned short* lb = Bsl + slot*(256*64) + (u-2)*(64*64);
      gld_lds16(wot + (size_t)(col0 + (u-2)*64 + r)*DIM + kt*64 + (k2 >> 1), (char*)lb + po);
    }
  };

  #pragma unroll
  for (int u = 0; u < 6; ++u) stage_unit(0, 0, u);

  int slot_cur = 0;
  for (int t = 0; t < 16; ++t){
    const bool nxt = (t + 1 < 16);
    const int slot_nxt = (slot_cur == 2) ? 0 : slot_cur + 1;
    const char* Ab = (const char*)(Asl + slot_cur*(128*64));
    const char* Bb = (const char*)(Bsl + slot_cur*(256*64));
    if (nxt){
      #pragma unroll
      for (int u = 0; u < 6; ++u) stage_unit(t + 1, slot_nxt, u);
      VMCNT(6);
    } else {
      VMCNT(0);
    }
    SCHED0();
    SBAR();
    SCHED0();
    bf16x8 b[4][2];
    #pragma unroll
    for (int nf = 0; nf < 4; ++nf){
      const int R = wn*64 + nf*16 + lo;
      #pragma unroll
      for (int ks = 0; ks < 2; ++ks){
        const int K2 = (ks*64 + hi*16) ^ ((R & 7) << 4);
        b[nf][ks] = *reinterpret_cast<const bf16x8*>(Bb + R*128 + K2);
      }
    }
    bf16x8 a0[2][2];
    #pragma unroll
    for (int mf = 0; mf < 2; ++mf){
      const int R = wm*64 + mf*16 + lo;
      #pragma unroll
      for (int ks = 0; ks < 2; ++ks){
        const int K2 = (ks*64 + hi*16) ^ ((R & 7) << 4);
        a0[mf][ks] = *reinterpret_cast<const bf16x8*>(Ab + R*128 + K2);
      }
    }
    __builtin_amdgcn_s_setprio(1);
    #pragma unroll
    for (int ks = 0; ks < 2; ++ks)
      #pragma unroll
      for (int mf = 0; mf < 2; ++mf)
        #pragma unroll
        for (int nf = 0; nf < 4; ++nf)
          acc[mf][nf] = __builtin_amdgcn_mfma_f32_16x16x32_bf16(
              a0[mf][ks], b[nf][ks], acc[mf][nf], 0, 0, 0);
    __builtin_amdgcn_s_setprio(0);
    bf16x8 a1[2][2];
    #pragma unroll
    for (int mf = 0; mf < 2; ++mf){
      const int R = wm*64 + (2 + mf)*16 + lo;
      #pragma unroll
      for (int ks = 0; ks < 2; ++ks){
        const int K2 = (ks*64 + hi*16) ^ ((R & 7) << 4);
        a1[mf][ks] = *reinterpret_cast<const bf16x8*>(Ab + R*128 + K2);
      }
    }
    __builtin_amdgcn_s_setprio(1);
    #pragma unroll
    for (int ks = 0; ks < 2; ++ks)
      #pragma unroll
      for (int mf = 0; mf < 2; ++mf)
        #pragma unroll
        for (int nf = 0; nf < 4; ++nf)
          acc[2+mf][nf] = __builtin_amdgcn_mfma_f32_16x16x32_bf16(
              a1[mf][ks], b[nf][ks], acc[2+mf][nf], 0, 0, 0);
    __builtin_amdgcn_s_setprio(0);
    slot_cur = slot_nxt;
  }

  #pragma unroll
  for (int nf = 0; nf < 4; ++nf){
    const int c = col0 + wn*64 + nf*16 + lo;
    const float boc = bo[c];
    #pragma unroll
    for (int mf = 0; mf < 4; ++mf){
      #pragma unroll
      for (int jj = 0; jj < 4; ++jj){
        const int r = row0 + wm*64 + mf*16 + hi*4 + jj;
        out[(size_t)r*DIM + c] = acc[mf][nf][jj] + boc;
      }
    }
  }
}

extern "C" void kernel_launch(void* const* d_in, const int* in_sizes, int n_in,
                              void* d_out, int out_size, void* d_ws, size_t ws_size,
                              hipStream_t stream){
  const float* x    = (const float*)d_in[0];
  const float* Wk   = (const float*)d_in[1];
  const float* bk   = (const float*)d_in[2];
  const float* Wv   = (const float*)d_in[3];
  const float* bv   = (const float*)d_in[4];
  const float* waft = (const float*)d_in[5];
  const float* Wo   = (const float*)d_in[6];
  const float* bo   = (const float*)d_in[7];
  float* out = (float*)d_out;

  char* w = (char*)d_ws;
  unsigned short* xb   = (unsigned short*)w; w += (size_t)ROWS*DIM*2;       // 16 MB
  unsigned short* wkt  = (unsigned short*)w; w += (size_t)DIM*DIM*2;        // 2 MB
  unsigned short* wvt  = (unsigned short*)w; w += (size_t)DIM*DIM*2;        // 2 MB
  unsigned short* wot  = (unsigned short*)w; w += (size_t)DIM*DIM*2;        // 2 MB
  unsigned short* ekb  = (unsigned short*)w; w += (size_t)HEADS*1024*SEQ*2; // 32 MB
  unsigned short* aftb = (unsigned short*)w; w += (size_t)ROWS*DIM*2;       // 16 MB
  unsigned short* ewb  = (unsigned short*)w; w += (size_t)HEADS*SEQ*SEQ*2;  // 64 MB

  k_prep<<<6912, 256, 0, stream>>>(x, Wk, Wv, Wo, waft, xb, wkt, wvt, wot, ewb);
  k_proj<<<256, 512, 0, stream>>>(xb, wkt, wvt, bk, bv, ekb);
  k_core<<<256, 512, 0, stream>>>(ewb, ekb, aftb);
  k_out<<<256, 512, 0, stream>>>(aftb, wot, bo, out);
}